// Round 1
// 698.520 us; speedup vs baseline: 1.0288x; 1.0288x over previous
//
#include <hip/hip_runtime.h>
#include <math.h>

// SuperpositionNeuron: out[r] = collapse(sigmoid(x@W+b) @ M^T) per row.
// Memory-bound: x is 512 MB of ~540 MB total traffic -> floor ~86 us @ 6.3 TB/s.
//
// V2 layout: 8 lanes per row-slice, each thread processes 4 CONSECUTIVE rows.
// 256-thread block handles 128 rows. Per load instruction j the wave still
// fetches 8 rows x 128 B contiguous segments (same dense pattern as V1), but:
//   - the 16 W float4 loads per thread now serve 4 rows (W L1 traffic /4)
//   - noise/u loaded as one float4 per 4 rows (broadcast across the 8 lanes)
//   - output stored as one coalesced float4 per 4 rows (32 B per wave store)
// Reduction: 3 shfl_xor levels within 8-lane groups, per row.
// Epilogue computed on ALL 8 lanes (same-address loads broadcast-coalesce);
// only the final float4 store is predicated on s==0.
__global__ __launch_bounds__(256) void superpos_kernel(
    const float4* __restrict__ x4,    // [B*32] (x as float4)
    const float4* __restrict__ W4,    // [128]  (W[k][0..3] per float4, row-major [D,S])
    const float*  __restrict__ bvec,  // [4]
    const float*  __restrict__ M,     // [16] row-major [S,S]
    const float*  __restrict__ thrp,  // [1]
    const float*  __restrict__ noise, // [B]
    const float*  __restrict__ u,     // [B]
    const float4* __restrict__ gum4,  // [B]  (gumbel rows as float4)
    float4*       __restrict__ out4,  // [B/4] (out as float4)
    int B)
{
    const int tid = threadIdx.x;
    const int s   = tid & 7;                          // sub-lane within row group
    const int g   = tid >> 3;                         // row-quad id within block, 0..31
    const int rbase = blockIdx.x * 128 + g * 4;       // first of this thread's 4 rows
    if (rbase >= B) return;

    const float4* __restrict__ x0 = x4 + (size_t)rbase * 32;

    float d[4][4];                                    // [row][state], statically indexed
    #pragma unroll
    for (int rr = 0; rr < 4; ++rr) {
        d[rr][0] = 0.f; d[rr][1] = 0.f; d[rr][2] = 0.f; d[rr][3] = 0.f;
    }

    #pragma unroll
    for (int j = 0; j < 4; ++j) {
        const int c = s + 8 * j;                      // float4-column index, 0..31
        const float4 w0 = W4[c * 4 + 0];
        const float4 w1 = W4[c * 4 + 1];
        const float4 w2 = W4[c * 4 + 2];
        const float4 w3 = W4[c * 4 + 3];
        #pragma unroll
        for (int rr = 0; rr < 4; ++rr) {
            const float4 xv = x0[rr * 32 + c];
            d[rr][0] += xv.x * w0.x + xv.y * w1.x + xv.z * w2.x + xv.w * w3.x;
            d[rr][1] += xv.x * w0.y + xv.y * w1.y + xv.z * w2.y + xv.w * w3.y;
            d[rr][2] += xv.x * w0.z + xv.y * w1.z + xv.z * w2.z + xv.w * w3.z;
            d[rr][3] += xv.x * w0.w + xv.y * w1.w + xv.z * w2.w + xv.w * w3.w;
        }
    }

    // Reduce across the 8 lanes of this row group (3 levels) for each row
    #pragma unroll
    for (int rr = 0; rr < 4; ++rr) {
        #pragma unroll
        for (int off = 4; off >= 1; off >>= 1) {
            d[rr][0] += __shfl_xor(d[rr][0], off, 8);
            d[rr][1] += __shfl_xor(d[rr][1], off, 8);
            d[rr][2] += __shfl_xor(d[rr][2], off, 8);
            d[rr][3] += __shfl_xor(d[rr][3], off, 8);
        }
    }
    // All 8 lanes now hold the full dot products for these 4 rows.

    const float b0 = bvec[0], b1 = bvec[1], b2 = bvec[2], b3 = bvec[3];
    const float thr = thrp[0];
    // noise/u for the 4 consecutive rows: one float4 each (16B-aligned, rbase%4==0)
    const float4 n4  = *reinterpret_cast<const float4*>(noise + rbase);
    const float4 uv4 = *reinterpret_cast<const float4*>(u + rbase);

    float res[4];
    #pragma unroll
    for (int rr = 0; rr < 4; ++rr) {
        // per-state sigmoid(Linear)
        const float st0 = 1.0f / (1.0f + expf(-(d[rr][0] + b0)));
        const float st1 = 1.0f / (1.0f + expf(-(d[rr][1] + b1)));
        const float st2 = 1.0f / (1.0f + expf(-(d[rr][2] + b2)));
        const float st3 = 1.0f / (1.0f + expf(-(d[rr][3] + b3)));

        // interfered[i] = sum_j st[j] * M[i][j]   (state @ M^T)
        const float i0 = st0*M[ 0] + st1*M[ 1] + st2*M[ 2] + st3*M[ 3];
        const float i1 = st0*M[ 4] + st1*M[ 5] + st2*M[ 6] + st3*M[ 7];
        const float i2 = st0*M[ 8] + st1*M[ 9] + st2*M[10] + st3*M[11];
        const float i3 = st0*M[12] + st1*M[13] + st2*M[14] + st3*M[15];

        // bernoulli collapse decision (rr is compile-time constant -> static select)
        const float nse = (rr == 0) ? n4.x : (rr == 1) ? n4.y : (rr == 2) ? n4.z : n4.w;
        const float uvv = (rr == 0) ? uv4.x : (rr == 1) ? uv4.y : (rr == 2) ? uv4.z : uv4.w;
        const float prob   = 1.0f / (1.0f + expf(-(nse + thr)));
        const bool  should = uvv < prob;

        // multinomial via gumbel argmax (first-max tie-break, like jnp.argmax)
        const float4 gv = gum4[rbase + rr];
        float best = i0 + gv.x; int ch = 0;
        float v;
        v = i1 + gv.y; if (v > best) { best = v; ch = 1; }
        v = i2 + gv.z; if (v > best) { best = v; ch = 2; }
        v = i3 + gv.w; if (v > best) { best = v; ch = 3; }
        const float meas = (ch == 0) ? i0 : (ch == 1) ? i1 : (ch == 2) ? i2 : i3;

        const float mean = 0.25f * (i0 + i1 + i2 + i3);
        res[rr] = should ? meas : mean;
    }

    if (s == 0) {
        out4[rbase >> 2] = make_float4(res[0], res[1], res[2], res[3]);
    }
}

extern "C" void kernel_launch(void* const* d_in, const int* in_sizes, int n_in,
                              void* d_out, int out_size, void* d_ws, size_t ws_size,
                              hipStream_t stream) {
    const float4* x4    = (const float4*)d_in[0];
    const float4* W4    = (const float4*)d_in[1];
    const float*  bvec  = (const float*)d_in[2];
    const float*  M     = (const float*)d_in[3];
    const float*  thrp  = (const float*)d_in[4];
    const float*  noise = (const float*)d_in[5];
    const float*  u     = (const float*)d_in[6];
    const float4* gum4  = (const float4*)d_in[7];
    float4*       out4  = (float4*)d_out;

    const int B = out_size;                 // [B,1] output
    const int grid = (B + 127) / 128;       // 128 rows per 256-thread block
    superpos_kernel<<<grid, 256, 0, stream>>>(x4, W4, bvec, M, thrp, noise, u,
                                              gum4, out4, B);
}

// Round 3
// 695.990 us; speedup vs baseline: 1.0326x; 1.0036x over previous
//
#include <hip/hip_runtime.h>
#include <math.h>

// SuperpositionNeuron: out[r] = collapse(sigmoid(x@W+b) @ M^T) per row.
// Memory-bound: x is 512 MB of ~540 MB total traffic -> floor ~86 us @ 6.3 TB/s
// (less with partial L3 residency of x).
//
// V4 = V3 with the lane-reduction bug fixed.
// Layout: 8 lanes per row-slice, each thread processes 8 CONSECUTIVE rows.
// 256-thread block handles 256 rows. Per x-load instruction the wave fetches
// 8 full 128-B cache lines (dense).
//   - W L1-hit load instructions per row: 2 (amortized over 8 rows)
//   - noise/u/store amortized over 8 rows (2 float4 loads, 2 float4 stores)
//   - lane reduction via DPP VALU adds, no DS traffic. All three levels are
//     INVOLUTIONS with unambiguous semantics (the V3 bug was row_ror:4,
//     whose shift direction gave lane 0 <- lane 12, a different row-octet):
//       level 1: quad_perm [1,0,3,2] (0xB1)  == xor 1
//       level 2: quad_perm [2,3,0,1] (0x4E)  == xor 2
//       level 3: row_half_mirror      (0x141) == lane k <-> lane 7-k in each
//                8-lane half; after levels 1-2 each lane holds its aligned
//                quad-sum, so mirror+add gives ALL 8 lanes the full sum.
__device__ __forceinline__ float dpp_add_xor1(float v) {
    int p = __builtin_amdgcn_update_dpp(0, __float_as_int(v), 0xB1, 0xF, 0xF, true);
    return v + __int_as_float(p);
}
__device__ __forceinline__ float dpp_add_xor2(float v) {
    int p = __builtin_amdgcn_update_dpp(0, __float_as_int(v), 0x4E, 0xF, 0xF, true);
    return v + __int_as_float(p);
}
__device__ __forceinline__ float dpp_add_halfmirror(float v) {
    int p = __builtin_amdgcn_update_dpp(0, __float_as_int(v), 0x141, 0xF, 0xF, true);
    return v + __int_as_float(p);
}

__global__ __launch_bounds__(256) void superpos_kernel(
    const float4* __restrict__ x4,    // [B*32] (x as float4)
    const float4* __restrict__ W4,    // [128]  (W[k][0..3] per float4, row-major [D,S])
    const float*  __restrict__ bvec,  // [4]
    const float*  __restrict__ M,     // [16] row-major [S,S]
    const float*  __restrict__ thrp,  // [1]
    const float*  __restrict__ noise, // [B]
    const float*  __restrict__ u,     // [B]
    const float4* __restrict__ gum4,  // [B]  (gumbel rows as float4)
    float4*       __restrict__ out4,  // [B/4] (out as float4)
    int B)
{
    const int tid = threadIdx.x;
    const int s   = tid & 7;                          // sub-lane within row group
    const int g   = tid >> 3;                         // row-octet id within block, 0..31
    const int rbase = blockIdx.x * 256 + g * 8;       // first of this thread's 8 rows
    if (rbase >= B) return;

    const float4* __restrict__ x0 = x4 + (size_t)rbase * 32;

    float d[8][4];                                    // [row][state], statically indexed
    #pragma unroll
    for (int rr = 0; rr < 8; ++rr) {
        d[rr][0] = 0.f; d[rr][1] = 0.f; d[rr][2] = 0.f; d[rr][3] = 0.f;
    }

    #pragma unroll
    for (int j = 0; j < 4; ++j) {
        const int c = s + 8 * j;                      // float4-column index, 0..31
        const float4 w0 = W4[c * 4 + 0];
        const float4 w1 = W4[c * 4 + 1];
        const float4 w2 = W4[c * 4 + 2];
        const float4 w3 = W4[c * 4 + 3];
        #pragma unroll
        for (int rr = 0; rr < 8; ++rr) {
            const float4 xv = x0[rr * 32 + c];
            d[rr][0] += xv.x * w0.x + xv.y * w1.x + xv.z * w2.x + xv.w * w3.x;
            d[rr][1] += xv.x * w0.y + xv.y * w1.y + xv.z * w2.y + xv.w * w3.y;
            d[rr][2] += xv.x * w0.z + xv.y * w1.z + xv.z * w2.z + xv.w * w3.z;
            d[rr][3] += xv.x * w0.w + xv.y * w1.w + xv.z * w2.w + xv.w * w3.w;
        }
    }

    // Reduce across the 8 lanes of this row group: 3 DPP VALU levels, no DS.
    // All levels are involutions; result valid on ALL lanes.
    #pragma unroll
    for (int rr = 0; rr < 8; ++rr) {
        #pragma unroll
        for (int k = 0; k < 4; ++k) {
            float v = d[rr][k];
            v = dpp_add_xor1(v);
            v = dpp_add_xor2(v);
            v = dpp_add_halfmirror(v);
            d[rr][k] = v;
        }
    }

    const float b0 = bvec[0], b1 = bvec[1], b2 = bvec[2], b3 = bvec[3];
    const float thr = thrp[0];
    // noise/u for the 8 consecutive rows: two float4 each (16B-aligned, rbase%8==0)
    const float4 n4a  = *reinterpret_cast<const float4*>(noise + rbase);
    const float4 n4b  = *reinterpret_cast<const float4*>(noise + rbase + 4);
    const float4 uv4a = *reinterpret_cast<const float4*>(u + rbase);
    const float4 uv4b = *reinterpret_cast<const float4*>(u + rbase + 4);

    float res[8];
    #pragma unroll
    for (int rr = 0; rr < 8; ++rr) {
        // per-state sigmoid(Linear)
        const float st0 = 1.0f / (1.0f + expf(-(d[rr][0] + b0)));
        const float st1 = 1.0f / (1.0f + expf(-(d[rr][1] + b1)));
        const float st2 = 1.0f / (1.0f + expf(-(d[rr][2] + b2)));
        const float st3 = 1.0f / (1.0f + expf(-(d[rr][3] + b3)));

        // interfered[i] = sum_j st[j] * M[i][j]   (state @ M^T)
        const float i0 = st0*M[ 0] + st1*M[ 1] + st2*M[ 2] + st3*M[ 3];
        const float i1 = st0*M[ 4] + st1*M[ 5] + st2*M[ 6] + st3*M[ 7];
        const float i2 = st0*M[ 8] + st1*M[ 9] + st2*M[10] + st3*M[11];
        const float i3 = st0*M[12] + st1*M[13] + st2*M[14] + st3*M[15];

        // bernoulli collapse decision (rr is compile-time constant -> static select)
        const float4 nlo = (rr < 4) ? n4a : n4b;
        const float4 ulo = (rr < 4) ? uv4a : uv4b;
        const int    q   = rr & 3;
        const float nse = (q == 0) ? nlo.x : (q == 1) ? nlo.y : (q == 2) ? nlo.z : nlo.w;
        const float uvv = (q == 0) ? ulo.x : (q == 1) ? ulo.y : (q == 2) ? ulo.z : ulo.w;
        const float prob   = 1.0f / (1.0f + expf(-(nse + thr)));
        const bool  should = uvv < prob;

        // multinomial via gumbel argmax (first-max tie-break, like jnp.argmax)
        const float4 gv = gum4[rbase + rr];
        float best = i0 + gv.x; int ch = 0;
        float v;
        v = i1 + gv.y; if (v > best) { best = v; ch = 1; }
        v = i2 + gv.z; if (v > best) { best = v; ch = 2; }
        v = i3 + gv.w; if (v > best) { best = v; ch = 3; }
        const float meas = (ch == 0) ? i0 : (ch == 1) ? i1 : (ch == 2) ? i2 : i3;

        const float mean = 0.25f * (i0 + i1 + i2 + i3);
        res[rr] = should ? meas : mean;
    }

    if (s == 0) {
        const int o = rbase >> 2;
        out4[o]     = make_float4(res[0], res[1], res[2], res[3]);
        out4[o + 1] = make_float4(res[4], res[5], res[6], res[7]);
    }
}

extern "C" void kernel_launch(void* const* d_in, const int* in_sizes, int n_in,
                              void* d_out, int out_size, void* d_ws, size_t ws_size,
                              hipStream_t stream) {
    const float4* x4    = (const float4*)d_in[0];
    const float4* W4    = (const float4*)d_in[1];
    const float*  bvec  = (const float*)d_in[2];
    const float*  M     = (const float*)d_in[3];
    const float*  thrp  = (const float*)d_in[4];
    const float*  noise = (const float*)d_in[5];
    const float*  u     = (const float*)d_in[6];
    const float4* gum4  = (const float4*)d_in[7];
    float4*       out4  = (float4*)d_out;

    const int B = out_size;                 // [B,1] output
    const int grid = (B + 255) / 256;       // 256 rows per 256-thread block
    superpos_kernel<<<grid, 256, 0, stream>>>(x4, W4, bvec, M, thrp, noise, u,
                                              gum4, out4, B);
}